// Round 1
// baseline (222.024 us; speedup 1.0000x reference)
//
#include <hip/hip_runtime.h>

// GATv2 x2 + LayerNorm, B=2 N=512 DIN=32 DH=DOUT=64 H=4. fp32 in/out.
// R11: attn_k was latency/barrier-bound (Occ 10%, VALUBusy 25%, 16 barriers/блок,
// 512 blocks = 2/CU). Split j 4-way (2048 blocks), stage whole 128-row tile once
// -> ONE barrier per block. Max-free softmax => partials combine exactly in the
// consumers (projln_k / ln2_k): out = sum(agg)/sum(lsum). mask_k: 128->256 blocks.

#define BB   2
#define NN   512
#define DIN  32
#define DH   64
#define HH   4
#define C1   256
#define C2   256
#define TI   8
#define NJC  4     // j-chunks per row block (128 j each)
#define XP   68    // xbuf pitch (floats), keeps 16B alignment, bank-spread
#define LEPS 1e-5f

typedef unsigned long long u64;

__device__ __forceinline__ float bf_sum(float v) {
#pragma unroll
    for (int o = 32; o > 0; o >>= 1) v += __shfl_xor(v, o, 64);
    return v;
}

// --- packed mask: bit j of mask64[i*8 + j/64] = (dot(emb_i,emb_j)!=0 || i==j)
// grid (NN/16, 8): one 16i x 64j tile per block, single barrier.
__global__ __launch_bounds__(256) void mask_k(const float* __restrict__ emb,
                                              u64* __restrict__ mask64) {
    __shared__ __align__(16) float s_ei[16][DH];
    __shared__ float ebuf[64][DH + 1];
    int it = blockIdx.x, jq = blockIdx.y;
    int t = threadIdx.x, lane = t & 63, iq = t >> 6;
    int j0 = jq * 64;
    {
        int row = t >> 4, d4 = (t & 15) << 2;
        *(float4*)&s_ei[row][d4] = *(const float4*)(emb + (it * 16 + row) * DH + d4);
    }
#pragma unroll
    for (int k = 0; k < 4; k++) {
        int idx = k * 256 + t, jl = idx >> 4, d4 = (idx & 15) << 2;
        float4 v = *(const float4*)(emb + (j0 + jl) * DH + d4);
        ebuf[jl][d4] = v.x; ebuf[jl][d4 + 1] = v.y;
        ebuf[jl][d4 + 2] = v.z; ebuf[jl][d4 + 3] = v.w;
    }
    __syncthreads();
    float acc[4] = {0.f, 0.f, 0.f, 0.f};
    for (int dc = 0; dc < 16; dc++) {
        int d = dc * 4;
        float e0 = ebuf[lane][d], e1 = ebuf[lane][d + 1];
        float e2 = ebuf[lane][d + 2], e3 = ebuf[lane][d + 3];
#pragma unroll
        for (int r = 0; r < 4; r++) {
            float4 iv = *(const float4*)&s_ei[iq * 4 + r][d];
            acc[r] += iv.x * e0 + iv.y * e1 + iv.z * e2 + iv.w * e3;
        }
    }
    int jg = j0 + lane;
#pragma unroll
    for (int r = 0; r < 4; r++) {
        int ig = it * 16 + iq * 4 + r;
        u64 bal = __ballot(acc[r] != 0.f || ig == jg);
        if (lane == 0) mask64[ig * 8 + jq] = bal;
    }
}

// --- proj1 + fused sl/sr: grid (BB*NN/4, 4 colquads), thread: 2 rows x 1 col ---
// sl[(h*BB+b)*NN + i] = 0.6 * att_h . xl[b,i,h,:]   (sr analogous from xr)
__global__ __launch_bounds__(256) void proj1_k(const float* __restrict__ x,
        const float* __restrict__ wl, const float* __restrict__ bl,
        const float* __restrict__ wr, const float* __restrict__ br,
        const float* __restrict__ att,
        float* __restrict__ xl, float* __restrict__ xr,
        float* __restrict__ sl, float* __restrict__ sr) {
    __shared__ float s_x[4][DIN];
    int t = threadIdx.x, lane = t & 63, row0 = blockIdx.x * 4, cq = blockIdx.y;
    if (t < 128) s_x[t >> 5][t & 31] = x[(row0 + (t >> 5)) * DIN + (t & 31)];
    __syncthreads();
    int cl = t & 127, half = t >> 7;
    int gc = cq * 128 + cl;
    const float* wbase; float bias; float* obase; float* sdst; int oc;
    if (gc < C1) { wbase = wl + gc; bias = bl[gc]; obase = xl; sdst = sl; oc = gc; }
    else         { wbase = wr + gc - C1; bias = br[gc - C1]; obase = xr; sdst = sr; oc = gc - C1; }
    int ra = half * 2, rb = ra + 1;
    float a0 = bias, a1 = bias;
#pragma unroll
    for (int k = 0; k < DIN; k++) {
        float wv = wbase[(size_t)k * C1];
        a0 += s_x[ra][k] * wv;
        a1 += s_x[rb][k] * wv;
    }
    obase[(size_t)(row0 + ra) * C1 + oc] = a0;
    obase[(size_t)(row0 + rb) * C1 + oc] = a1;
    float attv = att[oc];
    float s0 = bf_sum(attv * a0) * 0.6f;
    float s1 = bf_sum(attv * a1) * 0.6f;
    if (lane == 0) {
        int h = oc >> 6;
        int rwa = row0 + ra, rwb = row0 + rb;
        sdst[(h * BB + (rwa >> 9)) * NN + (rwa & 511)] = s0;
        sdst[(h * BB + (rwb >> 9)) * NN + (rwb & 511)] = s1;
    }
}

// --- combine partials + LN(g,be)+ReLU + proj2 + sl/sr. grid (BB*NN/4, 4) ---
__global__ __launch_bounds__(256) void projln_k(const float* __restrict__ pagg,
        const float* __restrict__ plsum, const float* __restrict__ abias,
        const float* __restrict__ g, const float* __restrict__ be,
        const float* __restrict__ wl, const float* __restrict__ bl,
        const float* __restrict__ wr, const float* __restrict__ br,
        const float* __restrict__ att,
        float* __restrict__ xl, float* __restrict__ xr,
        float* __restrict__ sl, float* __restrict__ sr) {
    __shared__ __align__(16) float s_h[4][C1];
    int t = threadIdx.x, lane = t & 63, w = t >> 6;
    int row0 = blockIdx.x * 4, cq = blockIdx.y;
    {
        int rgb = row0 + w;
        int bb = rgb >> 9, ii = rgb & 511;
        int c4 = lane << 2, hh = lane >> 4;
        float vx = 0.f, vy = 0.f, vz = 0.f, vw = 0.f, l = 0.f;
#pragma unroll
        for (int jc = 0; jc < NJC; jc++) {
            float4 a = *(const float4*)(pagg + ((size_t)jc * BB * NN + rgb) * C1 + c4);
            vx += a.x; vy += a.y; vz += a.z; vw += a.w;
            l += plsum[((size_t)jc * HH * BB + hh * BB + bb) * NN + ii];
        }
        float inv = 1.f / l;
        float4 bi = *(const float4*)(abias + c4);
        vx = vx * inv + bi.x; vy = vy * inv + bi.y;
        vz = vz * inv + bi.z; vw = vw * inv + bi.w;
        float mu = bf_sum(vx + vy + vz + vw) * (1.f / 256.f);
        float dx = vx - mu, dy = vy - mu, dz = vz - mu, dw = vw - mu;
        float var = bf_sum(dx * dx + dy * dy + dz * dz + dw * dw) * (1.f / 256.f);
        float rs = rsqrtf(var + LEPS);
        float4 gv = *(const float4*)(g + c4);
        float4 bv = *(const float4*)(be + c4);
        float4 y;
        y.x = fmaxf(dx * rs * gv.x + bv.x, 0.f);
        y.y = fmaxf(dy * rs * gv.y + bv.y, 0.f);
        y.z = fmaxf(dz * rs * gv.z + bv.z, 0.f);
        y.w = fmaxf(dw * rs * gv.w + bv.w, 0.f);
        *(float4*)&s_h[w][c4] = y;
    }
    __syncthreads();
    int cl = t & 127, half = t >> 7;
    int gc = cq * 128 + cl;
    const float* wbase; float bias; float* obase; float* sdst; int oc;
    if (gc < C2) { wbase = wl + gc; bias = bl[gc]; obase = xl; sdst = sl; oc = gc; }
    else         { wbase = wr + gc - C2; bias = br[gc - C2]; obase = xr; sdst = sr; oc = gc - C2; }
    int ra = half * 2, rb = ra + 1;
    float a0 = bias, a1 = bias;
#pragma unroll 8
    for (int k = 0; k < C1; k++) {
        float wv = wbase[(size_t)k * C2];
        a0 += s_h[ra][k] * wv;
        a1 += s_h[rb][k] * wv;
    }
    obase[(size_t)(row0 + ra) * C2 + oc] = a0;
    obase[(size_t)(row0 + rb) * C2 + oc] = a1;
    float attv = att[oc];
    float s0 = bf_sum(attv * a0) * 0.6f;
    float s1 = bf_sum(attv * a1) * 0.6f;
    if (lane == 0) {
        int h = oc >> 6;
        int rwa = row0 + ra, rwb = row0 + rb;
        sdst[(h * BB + (rwa >> 9)) * NN + (rwa & 511)] = s0;
        sdst[(h * BB + (rwb >> 9)) * NN + (rwb & 511)] = s1;
    }
}

// --- GATv2 attention, j-split. Block = (i-tile 8, j-chunk 128, h, b). 2048 blk.
// e = sl'[j] + sr'[i] + sum_d (0.4 a_d)|xl_jd + xr_id|; p = exp(e) (no-max,
// shift-invariant + bounded scores -> partials combine exactly).
// Whole chunk staged up front: ONE barrier, barrier-free main loop (s_p rows
// are wave-private). Writes partial agg + partial lsum; consumers combine.
__global__ __launch_bounds__(256) void attn_k(const float* __restrict__ xl,
        const float* __restrict__ xr, const float* __restrict__ att,
        const u64* __restrict__ mask64,
        const float* __restrict__ sl, const float* __restrict__ sr,
        float* __restrict__ pagg, float* __restrict__ plsum) {
    __shared__ __align__(16) float s_xr[TI][DH];
    __shared__ __align__(16) float s_att[DH];     // prescaled by 0.4
    __shared__ __align__(16) float xbuf[128][XP];
    __shared__ __align__(16) float s_p[TI][64];
    __shared__ __align__(16) float s_sl[128];     // prescaled by 0.6
    __shared__ float s_sr[TI];                    // prescaled by 0.6
    __shared__ u64 s_m64[TI * 2];

    int bx = blockIdx.x;
    int it = bx >> 2, jc = bx & 3;
    int h = blockIdx.y, b = blockIdx.z;
    int t = threadIdx.x, lane = t & 63, iq = t >> 6;
    int i0 = it * TI, j0 = jc * 128;

    const float* xlbase = xl + (size_t)b * NN * C1 + h * DH;
#pragma unroll
    for (int k = 0; k < 8; k++) {
        int idx = k * 256 + t, row = idx >> 4, d4 = (idx & 15) << 2;
        *(float4*)&xbuf[row][d4] = *(const float4*)(xlbase + (size_t)(j0 + row) * C1 + d4);
    }
    if (t < TI * 16) {   // 8 xr rows
        int row = t >> 4, d4 = (t & 15) << 2;
        *(float4*)&s_xr[row][d4] =
            *(const float4*)(xr + (size_t)(b * NN + i0 + row) * C1 + h * DH + d4);
    }
    if (t < DH) s_att[t] = att[h * DH + t] * 0.4f;
    if (t < TI) s_sr[t] = sr[(h * BB + b) * NN + i0 + t];
    if (t < TI * 2) s_m64[t] = mask64[(i0 + (t >> 1)) * 8 + jc * 2 + (t & 1)];
    if (t < 32) *(float4*)&s_sl[t << 2] = *(const float4*)(sl + (h * BB + b) * NN + j0 + (t << 2));
    __syncthreads();

    float rsr[2] = { s_sr[iq * 2], s_sr[iq * 2 + 1] };
    float lsum[2] = {0.f, 0.f}, agg[2] = {0.f, 0.f};

#pragma unroll
    for (int jt = 0; jt < 2; jt++) {
        int jl = jt * 64 + lane;
        // ---- |.|-scores for j = j0 + jl, rows iq*2, iq*2+1 ----
        float acc2[2] = {0.f, 0.f};
#pragma unroll
        for (int dc = 0; dc < 16; dc++) {
            float4 xv = *(const float4*)&xbuf[jl][dc << 2];
            float4 av = *(const float4*)&s_att[dc << 2];
#pragma unroll
            for (int r = 0; r < 2; r++) {
                float4 rv = *(const float4*)&s_xr[iq * 2 + r][dc << 2];
                float z0 = xv.x + rv.x, z1 = xv.y + rv.y;
                float z2 = xv.z + rv.z, z3 = xv.w + rv.w;
                acc2[r] = fmaf(av.x, fabsf(z0), acc2[r]);
                acc2[r] = fmaf(av.y, fabsf(z1), acc2[r]);
                acc2[r] = fmaf(av.z, fabsf(z2), acc2[r]);
                acc2[r] = fmaf(av.w, fabsf(z3), acc2[r]);
            }
        }
        float slv = s_sl[jl];
#pragma unroll
        for (int r = 0; r < 2; r++) {
            int il = iq * 2 + r;
            bool live = (s_m64[il * 2 + jt] >> lane) & 1ull;
            float e = slv + rsr[r] + acc2[r];
            float p = live ? __expf(e) : 0.f;
            lsum[r] += p;
            s_p[il][lane] = p;   // wave-private row: no barrier needed
        }
        __threadfence_block();

        // ---- aggregate tile: agg[r] (d = lane) += sum_j p_j * xl[j][d] ----
#pragma unroll
        for (int jq4 = 0; jq4 < 16; jq4++) {
            int j = jt * 64 + (jq4 << 2);
            float x0 = xbuf[j][lane], x1 = xbuf[j + 1][lane];
            float x2 = xbuf[j + 2][lane], x3 = xbuf[j + 3][lane];
#pragma unroll
            for (int r = 0; r < 2; r++) {
                float4 p = *(const float4*)&s_p[iq * 2 + r][jq4 << 2];
                agg[r] += p.x * x0 + p.y * x1 + p.z * x2 + p.w * x3;
            }
        }
        __threadfence_block();   // order s_p reuse across jt (same wave)
    }

#pragma unroll
    for (int r = 0; r < 2; r++) {
        int il = iq * 2 + r;
        float l = bf_sum(lsum[r]);
        pagg[((size_t)jc * BB * NN + b * NN + i0 + il) * C1 + h * DH + lane] = agg[r];
        if (lane == 0)
            plsum[((size_t)jc * HH * BB + h * BB + b) * NN + i0 + il] = l;
    }
}

// --- combine partials + final LayerNorm, wave-per-row ---
__global__ __launch_bounds__(256) void ln2_k(const float* __restrict__ pagg,
        const float* __restrict__ plsum, const float* __restrict__ abias,
        const float* __restrict__ g, const float* __restrict__ be,
        float* __restrict__ outp) {
    int t = threadIdx.x, lane = t & 63, w = t >> 6;
    int rgb = blockIdx.x * 4 + w;
    int bb = rgb >> 9, ii = rgb & 511;
    int c4 = lane << 2, hh = lane >> 4;
    float vx = 0.f, vy = 0.f, vz = 0.f, vw = 0.f, l = 0.f;
#pragma unroll
    for (int jc = 0; jc < NJC; jc++) {
        float4 a = *(const float4*)(pagg + ((size_t)jc * BB * NN + rgb) * C1 + c4);
        vx += a.x; vy += a.y; vz += a.z; vw += a.w;
        l += plsum[((size_t)jc * HH * BB + hh * BB + bb) * NN + ii];
    }
    float inv = 1.f / l;
    float4 bi = *(const float4*)(abias + c4);
    vx = vx * inv + bi.x; vy = vy * inv + bi.y;
    vz = vz * inv + bi.z; vw = vw * inv + bi.w;
    float mu = bf_sum(vx + vy + vz + vw) * (1.f / 256.f);
    float dx = vx - mu, dy = vy - mu, dz = vz - mu, dw = vw - mu;
    float var = bf_sum(dx * dx + dy * dy + dz * dz + dw * dw) * (1.f / 256.f);
    float rs = rsqrtf(var + LEPS);
    float4 gv = *(const float4*)(g + c4);
    float4 bv = *(const float4*)(be + c4);
    float4 y;
    y.x = dx * rs * gv.x + bv.x;
    y.y = dy * rs * gv.y + bv.y;
    y.z = dz * rs * gv.z + bv.z;
    y.w = dw * rs * gv.w + bv.w;
    *(float4*)(outp + (size_t)rgb * C1 + c4) = y;
}

extern "C" void kernel_launch(void* const* d_in, const int* in_sizes, int n_in,
                              void* d_out, int out_size, void* d_ws, size_t ws_size,
                              hipStream_t stream) {
    const float* x    = (const float*)d_in[0];
    const float* emb  = (const float*)d_in[1];
    const float* w1l  = (const float*)d_in[2];
    const float* b1l  = (const float*)d_in[3];
    const float* w1r  = (const float*)d_in[4];
    const float* b1r  = (const float*)d_in[5];
    const float* att1 = (const float*)d_in[6];
    const float* bia1 = (const float*)d_in[7];
    const float* g1   = (const float*)d_in[8];
    const float* be1  = (const float*)d_in[9];
    const float* w2l  = (const float*)d_in[10];
    const float* b2l  = (const float*)d_in[11];
    const float* w2r  = (const float*)d_in[12];
    const float* b2r  = (const float*)d_in[13];
    const float* att2 = (const float*)d_in[14];
    const float* bia2 = (const float*)d_in[15];
    const float* g2   = (const float*)d_in[16];
    const float* be2  = (const float*)d_in[17];

    char* w = (char*)d_ws;
    float* xl    = (float*)w; w += (size_t)BB * NN * C1 * 4;
    float* xr    = (float*)w; w += (size_t)BB * NN * C1 * 4;
    float* pagg  = (float*)w; w += (size_t)NJC * BB * NN * C1 * 4;
    u64* mask64  = (u64*)w;   w += (size_t)NN * 8 * 8;
    float* plsum = (float*)w; w += (size_t)NJC * HH * BB * NN * 4;
    float* sl    = (float*)w; w += (size_t)HH * BB * NN * 4;
    float* sr    = (float*)w; w += (size_t)HH * BB * NN * 4;

    mask_k<<<dim3(NN / 16, 8), 256, 0, stream>>>(emb, mask64);
    proj1_k<<<dim3(BB * NN / 4, 4), 256, 0, stream>>>(x, w1l, b1l, w1r, b1r, att1, xl, xr, sl, sr);
    attn_k<<<dim3((NN / TI) * NJC, HH, BB), 256, 0, stream>>>(xl, xr, att1, mask64, sl, sr, pagg, plsum);
    projln_k<<<dim3(BB * NN / 4, 4), 256, 0, stream>>>(pagg, plsum, bia1, g1, be1,
                                                       w2l, b2l, w2r, b2r, att2, xl, xr, sl, sr);
    attn_k<<<dim3((NN / TI) * NJC, HH, BB), 256, 0, stream>>>(xl, xr, att2, mask64, sl, sr, pagg, plsum);
    ln2_k<<<BB * NN / 4, 256, 0, stream>>>(pagg, plsum, bia2, g2, be2, (float*)d_out);
}

// Round 2
// 162.551 us; speedup vs baseline: 1.3659x; 1.3659x over previous
//
#include <hip/hip_runtime.h>

// GATv2 x2 + LayerNorm, B=2 N=512 DIN=32 DH=DOUT=64 H=4. fp32 in/out.
// R12: attn_k occupancy fix. R11 failed because VGPR 148->232 (compiler
// hoisted 16dc x 3 float4 LDS reads across the jt loop + 8 staged float4s)
// -> still 2 waves/SIMD. Now: (a) global_load_lds width=16 staging (zero
// VGPR cost), which forces (b) linear xbuf[128][64] + 16B-slot XOR swizzle
// (slot ^= j&7) applied via pre-swizzled GLOBAL source addresses — also
// removes the 8-way bank conflict the old pitch-68 layout had on b128
// score reads; (c) dc-outer score loop with acc[jt][r] so per-iteration
// operands die immediately. Target VGPR<=128 -> 4 blocks/CU.

#define BB   2
#define NN   512
#define DIN  32
#define DH   64
#define HH   4
#define C1   256
#define C2   256
#define TI   8
#define NJC  4     // j-chunks (128 j each)
#define LEPS 1e-5f

typedef unsigned long long u64;

__device__ __forceinline__ float bf_sum(float v) {
#pragma unroll
    for (int o = 32; o > 0; o >>= 1) v += __shfl_xor(v, o, 64);
    return v;
}

__device__ __forceinline__ void gload_lds16(const float* g, float* l) {
    __builtin_amdgcn_global_load_lds(
        (const __attribute__((address_space(1))) void*)g,
        (__attribute__((address_space(3))) void*)l, 16, 0, 0);
}

// --- packed mask: bit j of mask64[i*8 + j/64] = (dot(emb_i,emb_j)!=0 || i==j)
__global__ __launch_bounds__(256) void mask_k(const float* __restrict__ emb,
                                              u64* __restrict__ mask64) {
    __shared__ __align__(16) float s_ei[16][DH];
    __shared__ float ebuf[64][DH + 1];
    int it = blockIdx.x, jq = blockIdx.y;
    int t = threadIdx.x, lane = t & 63, iq = t >> 6;
    int j0 = jq * 64;
    {
        int row = t >> 4, d4 = (t & 15) << 2;
        *(float4*)&s_ei[row][d4] = *(const float4*)(emb + (it * 16 + row) * DH + d4);
    }
#pragma unroll
    for (int k = 0; k < 4; k++) {
        int idx = k * 256 + t, jl = idx >> 4, d4 = (idx & 15) << 2;
        float4 v = *(const float4*)(emb + (j0 + jl) * DH + d4);
        ebuf[jl][d4] = v.x; ebuf[jl][d4 + 1] = v.y;
        ebuf[jl][d4 + 2] = v.z; ebuf[jl][d4 + 3] = v.w;
    }
    __syncthreads();
    float acc[4] = {0.f, 0.f, 0.f, 0.f};
    for (int dc = 0; dc < 16; dc++) {
        int d = dc * 4;
        float e0 = ebuf[lane][d], e1 = ebuf[lane][d + 1];
        float e2 = ebuf[lane][d + 2], e3 = ebuf[lane][d + 3];
#pragma unroll
        for (int r = 0; r < 4; r++) {
            float4 iv = *(const float4*)&s_ei[iq * 4 + r][d];
            acc[r] += iv.x * e0 + iv.y * e1 + iv.z * e2 + iv.w * e3;
        }
    }
    int jg = j0 + lane;
#pragma unroll
    for (int r = 0; r < 4; r++) {
        int ig = it * 16 + iq * 4 + r;
        u64 bal = __ballot(acc[r] != 0.f || ig == jg);
        if (lane == 0) mask64[ig * 8 + jq] = bal;
    }
}

// --- proj1 + fused sl/sr ---
__global__ __launch_bounds__(256) void proj1_k(const float* __restrict__ x,
        const float* __restrict__ wl, const float* __restrict__ bl,
        const float* __restrict__ wr, const float* __restrict__ br,
        const float* __restrict__ att,
        float* __restrict__ xl, float* __restrict__ xr,
        float* __restrict__ sl, float* __restrict__ sr) {
    __shared__ float s_x[4][DIN];
    int t = threadIdx.x, lane = t & 63, row0 = blockIdx.x * 4, cq = blockIdx.y;
    if (t < 128) s_x[t >> 5][t & 31] = x[(row0 + (t >> 5)) * DIN + (t & 31)];
    __syncthreads();
    int cl = t & 127, half = t >> 7;
    int gc = cq * 128 + cl;
    const float* wbase; float bias; float* obase; float* sdst; int oc;
    if (gc < C1) { wbase = wl + gc; bias = bl[gc]; obase = xl; sdst = sl; oc = gc; }
    else         { wbase = wr + gc - C1; bias = br[gc - C1]; obase = xr; sdst = sr; oc = gc - C1; }
    int ra = half * 2, rb = ra + 1;
    float a0 = bias, a1 = bias;
#pragma unroll
    for (int k = 0; k < DIN; k++) {
        float wv = wbase[(size_t)k * C1];
        a0 += s_x[ra][k] * wv;
        a1 += s_x[rb][k] * wv;
    }
    obase[(size_t)(row0 + ra) * C1 + oc] = a0;
    obase[(size_t)(row0 + rb) * C1 + oc] = a1;
    float attv = att[oc];
    float s0 = bf_sum(attv * a0) * 0.6f;
    float s1 = bf_sum(attv * a1) * 0.6f;
    if (lane == 0) {
        int h = oc >> 6;
        int rwa = row0 + ra, rwb = row0 + rb;
        sdst[(h * BB + (rwa >> 9)) * NN + (rwa & 511)] = s0;
        sdst[(h * BB + (rwb >> 9)) * NN + (rwb & 511)] = s1;
    }
}

// --- combine partials + LN(g,be)+ReLU + proj2 + sl/sr ---
__global__ __launch_bounds__(256) void projln_k(const float* __restrict__ pagg,
        const float* __restrict__ plsum, const float* __restrict__ abias,
        const float* __restrict__ g, const float* __restrict__ be,
        const float* __restrict__ wl, const float* __restrict__ bl,
        const float* __restrict__ wr, const float* __restrict__ br,
        const float* __restrict__ att,
        float* __restrict__ xl, float* __restrict__ xr,
        float* __restrict__ sl, float* __restrict__ sr) {
    __shared__ __align__(16) float s_h[4][C1];
    int t = threadIdx.x, lane = t & 63, w = t >> 6;
    int row0 = blockIdx.x * 4, cq = blockIdx.y;
    {
        int rgb = row0 + w;
        int bb = rgb >> 9, ii = rgb & 511;
        int c4 = lane << 2, hh = lane >> 4;
        float vx = 0.f, vy = 0.f, vz = 0.f, vw = 0.f, l = 0.f;
#pragma unroll
        for (int jc = 0; jc < NJC; jc++) {
            float4 a = *(const float4*)(pagg + ((size_t)jc * BB * NN + rgb) * C1 + c4);
            vx += a.x; vy += a.y; vz += a.z; vw += a.w;
            l += plsum[((size_t)jc * HH * BB + hh * BB + bb) * NN + ii];
        }
        float inv = 1.f / l;
        float4 bi = *(const float4*)(abias + c4);
        vx = vx * inv + bi.x; vy = vy * inv + bi.y;
        vz = vz * inv + bi.z; vw = vw * inv + bi.w;
        float mu = bf_sum(vx + vy + vz + vw) * (1.f / 256.f);
        float dx = vx - mu, dy = vy - mu, dz = vz - mu, dw = vw - mu;
        float var = bf_sum(dx * dx + dy * dy + dz * dz + dw * dw) * (1.f / 256.f);
        float rs = rsqrtf(var + LEPS);
        float4 gv = *(const float4*)(g + c4);
        float4 bv = *(const float4*)(be + c4);
        float4 y;
        y.x = fmaxf(dx * rs * gv.x + bv.x, 0.f);
        y.y = fmaxf(dy * rs * gv.y + bv.y, 0.f);
        y.z = fmaxf(dz * rs * gv.z + bv.z, 0.f);
        y.w = fmaxf(dw * rs * gv.w + bv.w, 0.f);
        *(float4*)&s_h[w][c4] = y;
    }
    __syncthreads();
    int cl = t & 127, half = t >> 7;
    int gc = cq * 128 + cl;
    const float* wbase; float bias; float* obase; float* sdst; int oc;
    if (gc < C2) { wbase = wl + gc; bias = bl[gc]; obase = xl; sdst = sl; oc = gc; }
    else         { wbase = wr + gc - C2; bias = br[gc - C2]; obase = xr; sdst = sr; oc = gc - C2; }
    int ra = half * 2, rb = ra + 1;
    float a0 = bias, a1 = bias;
#pragma unroll 8
    for (int k = 0; k < C1; k++) {
        float wv = wbase[(size_t)k * C2];
        a0 += s_h[ra][k] * wv;
        a1 += s_h[rb][k] * wv;
    }
    obase[(size_t)(row0 + ra) * C2 + oc] = a0;
    obase[(size_t)(row0 + rb) * C2 + oc] = a1;
    float attv = att[oc];
    float s0 = bf_sum(attv * a0) * 0.6f;
    float s1 = bf_sum(attv * a1) * 0.6f;
    if (lane == 0) {
        int h = oc >> 6;
        int rwa = row0 + ra, rwb = row0 + rb;
        sdst[(h * BB + (rwa >> 9)) * NN + (rwa & 511)] = s0;
        sdst[(h * BB + (rwb >> 9)) * NN + (rwb & 511)] = s1;
    }
}

// --- GATv2 attention, j-split. Block = (i-tile 8, j-chunk 128, h, b). 2048 blk.
// xbuf linear [128][64] + 16B-slot XOR swizzle (slot ^= row&7), staged with
// global_load_lds(16B) from pre-swizzled global addresses. One barrier.
// Wave w owns i-rows w*2, w*2+1 (s_p rows wave-private -> fence only).
__global__ __launch_bounds__(256) void attn_k(const float* __restrict__ xl,
        const float* __restrict__ xr, const float* __restrict__ att,
        const u64* __restrict__ mask64,
        const float* __restrict__ sl, const float* __restrict__ sr,
        float* __restrict__ pagg, float* __restrict__ plsum) {
    __shared__ __align__(16) float xbuf[128 * 64];
    __shared__ __align__(16) float s_xr[TI][DH];
    __shared__ __align__(16) float s_att[DH];     // prescaled by 0.4
    __shared__ __align__(16) float s_p[TI][128];
    __shared__ __align__(16) float s_sl[128];     // prescaled by 0.6
    __shared__ float s_sr[TI];                    // prescaled by 0.6
    __shared__ u64 s_m64[TI * 2];

    int bx = blockIdx.x;
    int it = bx >> 2, jc = bx & 3;
    int h = blockIdx.y, b = blockIdx.z;
    int t = threadIdx.x, lane = t & 63, w = t >> 6;
    int i0 = it * TI, j0 = jc * 128;
    int w2 = w * 2;

    const float* xlbase = xl + (size_t)b * NN * C1 + h * DH;

    // ---- stage xbuf: wave w stages rows [w*32, w*32+32), 8 x 1KB loads ----
    {
        int jr0 = w * 32;
#pragma unroll
        for (int k = 0; k < 8; k++) {
            int jrow = jr0 + k * 4 + (lane >> 4);
            int dslot = (lane & 15) ^ (jrow & 7);          // pre-swizzled source
            const float* gp = xlbase + (size_t)(j0 + jrow) * C1 + (dslot << 2);
            gload_lds16(gp, &xbuf[(jr0 + k * 4) * 64]);    // wave-uniform dest
        }
    }
    if (t < TI * 16) {   // 8 xr rows
        int row = t >> 4, d4 = (t & 15) << 2;
        *(float4*)&s_xr[row][d4] =
            *(const float4*)(xr + (size_t)(b * NN + i0 + row) * C1 + h * DH + d4);
    }
    if (t < DH) s_att[t] = att[h * DH + t] * 0.4f;
    if (t < TI) s_sr[t] = sr[(h * BB + b) * NN + i0 + t];
    if (t < TI * 2) s_m64[t] = mask64[(i0 + (t >> 1)) * 8 + jc * 2 + (t & 1)];
    if (t < 32) *(float4*)&s_sl[t << 2] = *(const float4*)(sl + (h * BB + b) * NN + j0 + (t << 2));
    __syncthreads();

    float rsr0 = s_sr[w2], rsr1 = s_sr[w2 + 1];
    int swz = lane & 7;   // (jt*64+lane)&7 == lane&7 for both jt

    // ---- scores: lane = j (two j per thread: lane, 64+lane), rows w2, w2+1 ----
    float acc00 = 0.f, acc01 = 0.f, acc10 = 0.f, acc11 = 0.f;  // [jt][r]
#pragma unroll 4
    for (int dc = 0; dc < 16; dc++) {
        float4 av  = *(const float4*)&s_att[dc << 2];
        float4 rv0 = *(const float4*)&s_xr[w2][dc << 2];
        float4 rv1 = *(const float4*)&s_xr[w2 + 1][dc << 2];
        int so = (dc ^ swz) << 2;
        float4 xv0 = *(const float4*)&xbuf[lane * 64 + so];
        float4 xv1 = *(const float4*)&xbuf[(64 + lane) * 64 + so];
        acc00 = fmaf(av.x, fabsf(xv0.x + rv0.x), acc00);
        acc00 = fmaf(av.y, fabsf(xv0.y + rv0.y), acc00);
        acc00 = fmaf(av.z, fabsf(xv0.z + rv0.z), acc00);
        acc00 = fmaf(av.w, fabsf(xv0.w + rv0.w), acc00);
        acc01 = fmaf(av.x, fabsf(xv0.x + rv1.x), acc01);
        acc01 = fmaf(av.y, fabsf(xv0.y + rv1.y), acc01);
        acc01 = fmaf(av.z, fabsf(xv0.z + rv1.z), acc01);
        acc01 = fmaf(av.w, fabsf(xv0.w + rv1.w), acc01);
        acc10 = fmaf(av.x, fabsf(xv1.x + rv0.x), acc10);
        acc10 = fmaf(av.y, fabsf(xv1.y + rv0.y), acc10);
        acc10 = fmaf(av.z, fabsf(xv1.z + rv0.z), acc10);
        acc10 = fmaf(av.w, fabsf(xv1.w + rv0.w), acc10);
        acc11 = fmaf(av.x, fabsf(xv1.x + rv1.x), acc11);
        acc11 = fmaf(av.y, fabsf(xv1.y + rv1.y), acc11);
        acc11 = fmaf(av.z, fabsf(xv1.z + rv1.z), acc11);
        acc11 = fmaf(av.w, fabsf(xv1.w + rv1.w), acc11);
    }

    float slv0 = s_sl[lane], slv1 = s_sl[64 + lane];
    u64 m0a = s_m64[w2 * 2 + 0],       m0b = s_m64[w2 * 2 + 1];
    u64 m1a = s_m64[(w2 + 1) * 2 + 0], m1b = s_m64[(w2 + 1) * 2 + 1];
    float p00 = ((m0a >> lane) & 1ull) ? __expf(slv0 + rsr0 + acc00) : 0.f; // jt0,r0
    float p01 = ((m1a >> lane) & 1ull) ? __expf(slv0 + rsr1 + acc01) : 0.f; // jt0,r1
    float p10 = ((m0b >> lane) & 1ull) ? __expf(slv1 + rsr0 + acc10) : 0.f; // jt1,r0
    float p11 = ((m1b >> lane) & 1ull) ? __expf(slv1 + rsr1 + acc11) : 0.f; // jt1,r1
    s_p[w2][lane]          = p00;
    s_p[w2 + 1][lane]      = p01;
    s_p[w2][64 + lane]     = p10;
    s_p[w2 + 1][64 + lane] = p11;
    float lsum0 = p00 + p10;
    float lsum1 = p01 + p11;
    __threadfence_block();   // wave-private s_p rows: no barrier needed

    // ---- aggregate: lane = d, agg[r] += sum_j p_j * xbuf[j][d] ----
    int l2 = lane >> 2, lm = lane & 3;
    int off[8];
#pragma unroll
    for (int v = 0; v < 8; v++) off[v] = (((l2 ^ v) << 2) | lm);

    float agg0 = 0.f, agg1 = 0.f;
#pragma unroll 2
    for (int j8 = 0; j8 < 16; j8++) {
        int rb = j8 * 512;   // 8 rows * 64 dwords
        float4 pa0 = *(const float4*)&s_p[w2][j8 * 8];
        float4 pb0 = *(const float4*)&s_p[w2][j8 * 8 + 4];
        float4 pa1 = *(const float4*)&s_p[w2 + 1][j8 * 8];
        float4 pb1 = *(const float4*)&s_p[w2 + 1][j8 * 8 + 4];
        float x0 = xbuf[rb +   0 + off[0]];
        float x1 = xbuf[rb +  64 + off[1]];
        float x2 = xbuf[rb + 128 + off[2]];
        float x3 = xbuf[rb + 192 + off[3]];
        float x4 = xbuf[rb + 256 + off[4]];
        float x5 = xbuf[rb + 320 + off[5]];
        float x6 = xbuf[rb + 384 + off[6]];
        float x7 = xbuf[rb + 448 + off[7]];
        agg0 += pa0.x * x0 + pa0.y * x1 + pa0.z * x2 + pa0.w * x3
              + pb0.x * x4 + pb0.y * x5 + pb0.z * x6 + pb0.w * x7;
        agg1 += pa1.x * x0 + pa1.y * x1 + pa1.z * x2 + pa1.w * x3
              + pb1.x * x4 + pb1.y * x5 + pb1.z * x6 + pb1.w * x7;
    }

    float l0 = bf_sum(lsum0), l1 = bf_sum(lsum1);
    size_t orow = ((size_t)jc * BB * NN + b * NN + i0 + w2) * C1 + h * DH + lane;
    pagg[orow] = agg0;
    pagg[orow + C1] = agg1;
    if (lane == 0) {
        plsum[((size_t)jc * HH * BB + h * BB + b) * NN + i0 + w2] = l0;
        plsum[((size_t)jc * HH * BB + h * BB + b) * NN + i0 + w2 + 1] = l1;
    }
}

// --- combine partials + final LayerNorm, wave-per-row ---
__global__ __launch_bounds__(256) void ln2_k(const float* __restrict__ pagg,
        const float* __restrict__ plsum, const float* __restrict__ abias,
        const float* __restrict__ g, const float* __restrict__ be,
        float* __restrict__ outp) {
    int t = threadIdx.x, lane = t & 63, w = t >> 6;
    int rgb = blockIdx.x * 4 + w;
    int bb = rgb >> 9, ii = rgb & 511;
    int c4 = lane << 2, hh = lane >> 4;
    float vx = 0.f, vy = 0.f, vz = 0.f, vw = 0.f, l = 0.f;
#pragma unroll
    for (int jc = 0; jc < NJC; jc++) {
        float4 a = *(const float4*)(pagg + ((size_t)jc * BB * NN + rgb) * C1 + c4);
        vx += a.x; vy += a.y; vz += a.z; vw += a.w;
        l += plsum[((size_t)jc * HH * BB + hh * BB + bb) * NN + ii];
    }
    float inv = 1.f / l;
    float4 bi = *(const float4*)(abias + c4);
    vx = vx * inv + bi.x; vy = vy * inv + bi.y;
    vz = vz * inv + bi.z; vw = vw * inv + bi.w;
    float mu = bf_sum(vx + vy + vz + vw) * (1.f / 256.f);
    float dx = vx - mu, dy = vy - mu, dz = vz - mu, dw = vw - mu;
    float var = bf_sum(dx * dx + dy * dy + dz * dz + dw * dw) * (1.f / 256.f);
    float rs = rsqrtf(var + LEPS);
    float4 gv = *(const float4*)(g + c4);
    float4 bv = *(const float4*)(be + c4);
    float4 y;
    y.x = dx * rs * gv.x + bv.x;
    y.y = dy * rs * gv.y + bv.y;
    y.z = dz * rs * gv.z + bv.z;
    y.w = dw * rs * gv.w + bv.w;
    *(float4*)(outp + (size_t)rgb * C1 + c4) = y;
}

extern "C" void kernel_launch(void* const* d_in, const int* in_sizes, int n_in,
                              void* d_out, int out_size, void* d_ws, size_t ws_size,
                              hipStream_t stream) {
    const float* x    = (const float*)d_in[0];
    const float* emb  = (const float*)d_in[1];
    const float* w1l  = (const float*)d_in[2];
    const float* b1l  = (const float*)d_in[3];
    const float* w1r  = (const float*)d_in[4];
    const float* b1r  = (const float*)d_in[5];
    const float* att1 = (const float*)d_in[6];
    const float* bia1 = (const float*)d_in[7];
    const float* g1   = (const float*)d_in[8];
    const float* be1  = (const float*)d_in[9];
    const float* w2l  = (const float*)d_in[10];
    const float* b2l  = (const float*)d_in[11];
    const float* w2r  = (const float*)d_in[12];
    const float* b2r  = (const float*)d_in[13];
    const float* att2 = (const float*)d_in[14];
    const float* bia2 = (const float*)d_in[15];
    const float* g2   = (const float*)d_in[16];
    const float* be2  = (const float*)d_in[17];

    char* w = (char*)d_ws;
    float* xl    = (float*)w; w += (size_t)BB * NN * C1 * 4;
    float* xr    = (float*)w; w += (size_t)BB * NN * C1 * 4;
    float* pagg  = (float*)w; w += (size_t)NJC * BB * NN * C1 * 4;
    u64* mask64  = (u64*)w;   w += (size_t)NN * 8 * 8;
    float* plsum = (float*)w; w += (size_t)NJC * HH * BB * NN * 4;
    float* sl    = (float*)w; w += (size_t)HH * BB * NN * 4;
    float* sr    = (float*)w; w += (size_t)HH * BB * NN * 4;

    mask_k<<<dim3(NN / 16, 8), 256, 0, stream>>>(emb, mask64);
    proj1_k<<<dim3(BB * NN / 4, 4), 256, 0, stream>>>(x, w1l, b1l, w1r, b1r, att1, xl, xr, sl, sr);
    attn_k<<<dim3((NN / TI) * NJC, HH, BB), 256, 0, stream>>>(xl, xr, att1, mask64, sl, sr, pagg, plsum);
    projln_k<<<dim3(BB * NN / 4, 4), 256, 0, stream>>>(pagg, plsum, bia1, g1, be1,
                                                       w2l, b2l, w2r, b2r, att2, xl, xr, sl, sr);
    attn_k<<<dim3((NN / TI) * NJC, HH, BB), 256, 0, stream>>>(xl, xr, att2, mask64, sl, sr, pagg, plsum);
    ln2_k<<<BB * NN / 4, 256, 0, stream>>>(pagg, plsum, bia2, g2, be2, (float*)d_out);
}

// Round 4
// 162.278 us; speedup vs baseline: 1.3682x; 1.0017x over previous
//
#include <hip/hip_runtime.h>

// GATv2 x2 + LayerNorm, B=2 N=512 DIN=32 DH=DOUT=64 H=4. fp32 in/out.
// R14 == R13 resubmitted verbatim (R13 bench died with "container failed
// twice" — infra error, no kernel verdict; audit found no hang/fault path).
// R13: attn_k s_p elimination. R2 counters: top-5 = 256MiB poison fills
// (2x40.6us, harness-fixed); attn ~29us each (inferred). attn LDS traffic
// was ~half s_p round-trip (store+fence+64 b128+128 b32 reads). Now p stays
// in registers; aggregate: lane owns d-chunk (lane&15)*4 of row-subset
// lane>>4, ds_read_b128 per 4-row group (32 reads, bank-floor, imm-offset
// addressing via swizzle parity), p broadcast via __shfl(ds_bpermute),
// butterfly (xor 16,32) + float4 stores from lanes 0..31.

#define BB   2
#define NN   512
#define DIN  32
#define DH   64
#define HH   4
#define C1   256
#define C2   256
#define TI   8
#define NJC  4     // j-chunks (128 j each)
#define LEPS 1e-5f

typedef unsigned long long u64;

__device__ __forceinline__ float bf_sum(float v) {
#pragma unroll
    for (int o = 32; o > 0; o >>= 1) v += __shfl_xor(v, o, 64);
    return v;
}

__device__ __forceinline__ void gload_lds16(const float* g, float* l) {
    __builtin_amdgcn_global_load_lds(
        (const __attribute__((address_space(1))) void*)g,
        (__attribute__((address_space(3))) void*)l, 16, 0, 0);
}

// --- packed mask: bit j of mask64[i*8 + j/64] = (dot(emb_i,emb_j)!=0 || i==j)
__global__ __launch_bounds__(256) void mask_k(const float* __restrict__ emb,
                                              u64* __restrict__ mask64) {
    __shared__ __align__(16) float s_ei[16][DH];
    __shared__ float ebuf[64][DH + 1];
    int it = blockIdx.x, jq = blockIdx.y;
    int t = threadIdx.x, lane = t & 63, iq = t >> 6;
    int j0 = jq * 64;
    {
        int row = t >> 4, d4 = (t & 15) << 2;
        *(float4*)&s_ei[row][d4] = *(const float4*)(emb + (it * 16 + row) * DH + d4);
    }
#pragma unroll
    for (int k = 0; k < 4; k++) {
        int idx = k * 256 + t, jl = idx >> 4, d4 = (idx & 15) << 2;
        float4 v = *(const float4*)(emb + (j0 + jl) * DH + d4);
        ebuf[jl][d4] = v.x; ebuf[jl][d4 + 1] = v.y;
        ebuf[jl][d4 + 2] = v.z; ebuf[jl][d4 + 3] = v.w;
    }
    __syncthreads();
    float acc[4] = {0.f, 0.f, 0.f, 0.f};
    for (int dc = 0; dc < 16; dc++) {
        int d = dc * 4;
        float e0 = ebuf[lane][d], e1 = ebuf[lane][d + 1];
        float e2 = ebuf[lane][d + 2], e3 = ebuf[lane][d + 3];
#pragma unroll
        for (int r = 0; r < 4; r++) {
            float4 iv = *(const float4*)&s_ei[iq * 4 + r][d];
            acc[r] += iv.x * e0 + iv.y * e1 + iv.z * e2 + iv.w * e3;
        }
    }
    int jg = j0 + lane;
#pragma unroll
    for (int r = 0; r < 4; r++) {
        int ig = it * 16 + iq * 4 + r;
        u64 bal = __ballot(acc[r] != 0.f || ig == jg);
        if (lane == 0) mask64[ig * 8 + jq] = bal;
    }
}

// --- proj1 + fused sl/sr ---
__global__ __launch_bounds__(256) void proj1_k(const float* __restrict__ x,
        const float* __restrict__ wl, const float* __restrict__ bl,
        const float* __restrict__ wr, const float* __restrict__ br,
        const float* __restrict__ att,
        float* __restrict__ xl, float* __restrict__ xr,
        float* __restrict__ sl, float* __restrict__ sr) {
    __shared__ float s_x[4][DIN];
    int t = threadIdx.x, lane = t & 63, row0 = blockIdx.x * 4, cq = blockIdx.y;
    if (t < 128) s_x[t >> 5][t & 31] = x[(row0 + (t >> 5)) * DIN + (t & 31)];
    __syncthreads();
    int cl = t & 127, half = t >> 7;
    int gc = cq * 128 + cl;
    const float* wbase; float bias; float* obase; float* sdst; int oc;
    if (gc < C1) { wbase = wl + gc; bias = bl[gc]; obase = xl; sdst = sl; oc = gc; }
    else         { wbase = wr + gc - C1; bias = br[gc - C1]; obase = xr; sdst = sr; oc = gc - C1; }
    int ra = half * 2, rb = ra + 1;
    float a0 = bias, a1 = bias;
#pragma unroll
    for (int k = 0; k < DIN; k++) {
        float wv = wbase[(size_t)k * C1];
        a0 += s_x[ra][k] * wv;
        a1 += s_x[rb][k] * wv;
    }
    obase[(size_t)(row0 + ra) * C1 + oc] = a0;
    obase[(size_t)(row0 + rb) * C1 + oc] = a1;
    float attv = att[oc];
    float s0 = bf_sum(attv * a0) * 0.6f;
    float s1 = bf_sum(attv * a1) * 0.6f;
    if (lane == 0) {
        int h = oc >> 6;
        int rwa = row0 + ra, rwb = row0 + rb;
        sdst[(h * BB + (rwa >> 9)) * NN + (rwa & 511)] = s0;
        sdst[(h * BB + (rwb >> 9)) * NN + (rwb & 511)] = s1;
    }
}

// --- combine partials + LN(g,be)+ReLU + proj2 + sl/sr ---
__global__ __launch_bounds__(256) void projln_k(const float* __restrict__ pagg,
        const float* __restrict__ plsum, const float* __restrict__ abias,
        const float* __restrict__ g, const float* __restrict__ be,
        const float* __restrict__ wl, const float* __restrict__ bl,
        const float* __restrict__ wr, const float* __restrict__ br,
        const float* __restrict__ att,
        float* __restrict__ xl, float* __restrict__ xr,
        float* __restrict__ sl, float* __restrict__ sr) {
    __shared__ __align__(16) float s_h[4][C1];
    int t = threadIdx.x, lane = t & 63, w = t >> 6;
    int row0 = blockIdx.x * 4, cq = blockIdx.y;
    {
        int rgb = row0 + w;
        int bb = rgb >> 9, ii = rgb & 511;
        int c4 = lane << 2, hh = lane >> 4;
        float vx = 0.f, vy = 0.f, vz = 0.f, vw = 0.f, l = 0.f;
#pragma unroll
        for (int jc = 0; jc < NJC; jc++) {
            float4 a = *(const float4*)(pagg + ((size_t)jc * BB * NN + rgb) * C1 + c4);
            vx += a.x; vy += a.y; vz += a.z; vw += a.w;
            l += plsum[((size_t)jc * HH * BB + hh * BB + bb) * NN + ii];
        }
        float inv = 1.f / l;
        float4 bi = *(const float4*)(abias + c4);
        vx = vx * inv + bi.x; vy = vy * inv + bi.y;
        vz = vz * inv + bi.z; vw = vw * inv + bi.w;
        float mu = bf_sum(vx + vy + vz + vw) * (1.f / 256.f);
        float dx = vx - mu, dy = vy - mu, dz = vz - mu, dw = vw - mu;
        float var = bf_sum(dx * dx + dy * dy + dz * dz + dw * dw) * (1.f / 256.f);
        float rs = rsqrtf(var + LEPS);
        float4 gv = *(const float4*)(g + c4);
        float4 bv = *(const float4*)(be + c4);
        float4 y;
        y.x = fmaxf(dx * rs * gv.x + bv.x, 0.f);
        y.y = fmaxf(dy * rs * gv.y + bv.y, 0.f);
        y.z = fmaxf(dz * rs * gv.z + bv.z, 0.f);
        y.w = fmaxf(dw * rs * gv.w + bv.w, 0.f);
        *(float4*)&s_h[w][c4] = y;
    }
    __syncthreads();
    int cl = t & 127, half = t >> 7;
    int gc = cq * 128 + cl;
    const float* wbase; float bias; float* obase; float* sdst; int oc;
    if (gc < C2) { wbase = wl + gc; bias = bl[gc]; obase = xl; sdst = sl; oc = gc; }
    else         { wbase = wr + gc - C2; bias = br[gc - C2]; obase = xr; sdst = sr; oc = gc - C2; }
    int ra = half * 2, rb = ra + 1;
    float a0 = bias, a1 = bias;
#pragma unroll 8
    for (int k = 0; k < C1; k++) {
        float wv = wbase[(size_t)k * C2];
        a0 += s_h[ra][k] * wv;
        a1 += s_h[rb][k] * wv;
    }
    obase[(size_t)(row0 + ra) * C2 + oc] = a0;
    obase[(size_t)(row0 + rb) * C2 + oc] = a1;
    float attv = att[oc];
    float s0 = bf_sum(attv * a0) * 0.6f;
    float s1 = bf_sum(attv * a1) * 0.6f;
    if (lane == 0) {
        int h = oc >> 6;
        int rwa = row0 + ra, rwb = row0 + rb;
        sdst[(h * BB + (rwa >> 9)) * NN + (rwa & 511)] = s0;
        sdst[(h * BB + (rwb >> 9)) * NN + (rwb & 511)] = s1;
    }
}

// --- GATv2 attention, j-split. Block = (i-tile 8, j-chunk 128, h, b). 2048 blk.
// xbuf linear [128][64] + 16B-slot XOR swizzle (slot ^= row&7), staged with
// global_load_lds(16B) from pre-swizzled global addresses. One barrier.
// Wave w owns i-rows w*2, w*2+1. p kept in registers; aggregate via per-lane
// d-chunk b128 reads + __shfl p-broadcast; butterfly finish.
__global__ __launch_bounds__(256) void attn_k(const float* __restrict__ xl,
        const float* __restrict__ xr, const float* __restrict__ att,
        const u64* __restrict__ mask64,
        const float* __restrict__ sl, const float* __restrict__ sr,
        float* __restrict__ pagg, float* __restrict__ plsum) {
    __shared__ __align__(16) float xbuf[128 * 64];
    __shared__ __align__(16) float s_xr[TI][DH];
    __shared__ __align__(16) float s_att[DH];     // prescaled by 0.4
    __shared__ __align__(16) float s_sl[128];     // prescaled by 0.6
    __shared__ float s_sr[TI];                    // prescaled by 0.6
    __shared__ u64 s_m64[TI * 2];

    int bx = blockIdx.x;
    int it = bx >> 2, jc = bx & 3;
    int h = blockIdx.y, b = blockIdx.z;
    int t = threadIdx.x, lane = t & 63, w = t >> 6;
    int i0 = it * TI, j0 = jc * 128;
    int w2 = w * 2;

    const float* xlbase = xl + (size_t)b * NN * C1 + h * DH;

    // ---- stage xbuf: wave w stages rows [w*32, w*32+32), 8 x 1KB loads ----
    {
        int jr0 = w * 32;
#pragma unroll
        for (int k = 0; k < 8; k++) {
            int jrow = jr0 + k * 4 + (lane >> 4);
            int dslot = (lane & 15) ^ (jrow & 7);          // pre-swizzled source
            const float* gp = xlbase + (size_t)(j0 + jrow) * C1 + (dslot << 2);
            gload_lds16(gp, &xbuf[(jr0 + k * 4) * 64]);    // wave-uniform dest
        }
    }
    if (t < TI * 16) {   // 8 xr rows
        int row = t >> 4, d4 = (t & 15) << 2;
        *(float4*)&s_xr[row][d4] =
            *(const float4*)(xr + (size_t)(b * NN + i0 + row) * C1 + h * DH + d4);
    }
    if (t < DH) s_att[t] = att[h * DH + t] * 0.4f;
    if (t < TI) s_sr[t] = sr[(h * BB + b) * NN + i0 + t];
    if (t < TI * 2) s_m64[t] = mask64[(i0 + (t >> 1)) * 8 + jc * 2 + (t & 1)];
    if (t < 32) *(float4*)&s_sl[t << 2] = *(const float4*)(sl + (h * BB + b) * NN + j0 + (t << 2));
    __syncthreads();

    float rsr0 = s_sr[w2], rsr1 = s_sr[w2 + 1];
    int swz = lane & 7;   // (jt*64+lane)&7 == lane&7 for both jt

    // ---- scores: lane = j (two j per thread: lane, 64+lane), rows w2, w2+1 ----
    float acc00 = 0.f, acc01 = 0.f, acc10 = 0.f, acc11 = 0.f;  // [jt][r]
#pragma unroll 4
    for (int dc = 0; dc < 16; dc++) {
        float4 av  = *(const float4*)&s_att[dc << 2];
        float4 rv0 = *(const float4*)&s_xr[w2][dc << 2];
        float4 rv1 = *(const float4*)&s_xr[w2 + 1][dc << 2];
        int so = (dc ^ swz) << 2;
        float4 xv0 = *(const float4*)&xbuf[lane * 64 + so];
        float4 xv1 = *(const float4*)&xbuf[(64 + lane) * 64 + so];
        acc00 = fmaf(av.x, fabsf(xv0.x + rv0.x), acc00);
        acc00 = fmaf(av.y, fabsf(xv0.y + rv0.y), acc00);
        acc00 = fmaf(av.z, fabsf(xv0.z + rv0.z), acc00);
        acc00 = fmaf(av.w, fabsf(xv0.w + rv0.w), acc00);
        acc01 = fmaf(av.x, fabsf(xv0.x + rv1.x), acc01);
        acc01 = fmaf(av.y, fabsf(xv0.y + rv1.y), acc01);
        acc01 = fmaf(av.z, fabsf(xv0.z + rv1.z), acc01);
        acc01 = fmaf(av.w, fabsf(xv0.w + rv1.w), acc01);
        acc10 = fmaf(av.x, fabsf(xv1.x + rv0.x), acc10);
        acc10 = fmaf(av.y, fabsf(xv1.y + rv0.y), acc10);
        acc10 = fmaf(av.z, fabsf(xv1.z + rv0.z), acc10);
        acc10 = fmaf(av.w, fabsf(xv1.w + rv0.w), acc10);
        acc11 = fmaf(av.x, fabsf(xv1.x + rv1.x), acc11);
        acc11 = fmaf(av.y, fabsf(xv1.y + rv1.y), acc11);
        acc11 = fmaf(av.z, fabsf(xv1.z + rv1.z), acc11);
        acc11 = fmaf(av.w, fabsf(xv1.w + rv1.w), acc11);
    }

    float slv0 = s_sl[lane], slv1 = s_sl[64 + lane];
    u64 m0a = s_m64[w2 * 2 + 0],       m0b = s_m64[w2 * 2 + 1];
    u64 m1a = s_m64[(w2 + 1) * 2 + 0], m1b = s_m64[(w2 + 1) * 2 + 1];
    float p00 = ((m0a >> lane) & 1ull) ? __expf(slv0 + rsr0 + acc00) : 0.f; // j=lane,    r0
    float p01 = ((m1a >> lane) & 1ull) ? __expf(slv0 + rsr1 + acc01) : 0.f; // j=lane,    r1
    float p10 = ((m0b >> lane) & 1ull) ? __expf(slv1 + rsr0 + acc10) : 0.f; // j=64+lane, r0
    float p11 = ((m1b >> lane) & 1ull) ? __expf(slv1 + rsr1 + acc11) : 0.f; // j=64+lane, r1
    float lsum0 = p00 + p10;
    float lsum1 = p01 + p11;

    // ---- aggregate: lane owns d-chunk (lane&15)*4 of row-subset q=lane>>4 ----
    // row = j8*4+q; stored slot16 = c16 ^ (row&7) = c16 ^ q ^ 4*(j8&1)
    int q = lane >> 4, c16 = lane & 15;
    const float* be_ = &xbuf[q * 64 + ((c16 ^ q) << 2)];       // even j8 rows
    const float* bo_ = &xbuf[q * 64 + ((c16 ^ q ^ 4) << 2)];   // odd  j8 rows
    float4 a0 = {0.f, 0.f, 0.f, 0.f}, a1 = {0.f, 0.f, 0.f, 0.f};
#pragma unroll
    for (int j8 = 0; j8 < 16; j8++) {
        const float* bp = (j8 & 1) ? bo_ : be_;
        float4 xv = *(const float4*)(bp + j8 * 256);   // row j8*4+q
        int sj = j8 * 4 + q;
        float pr0 = __shfl(p00, sj, 64);
        float pr1 = __shfl(p01, sj, 64);
        a0.x += pr0 * xv.x; a0.y += pr0 * xv.y; a0.z += pr0 * xv.z; a0.w += pr0 * xv.w;
        a1.x += pr1 * xv.x; a1.y += pr1 * xv.y; a1.z += pr1 * xv.z; a1.w += pr1 * xv.w;
    }
#pragma unroll
    for (int j8 = 16; j8 < 32; j8++) {
        const float* bp = (j8 & 1) ? bo_ : be_;
        float4 xv = *(const float4*)(bp + j8 * 256);   // row j8*4+q (j >= 64)
        int sj = (j8 - 16) * 4 + q;
        float pr0 = __shfl(p10, sj, 64);
        float pr1 = __shfl(p11, sj, 64);
        a0.x += pr0 * xv.x; a0.y += pr0 * xv.y; a0.z += pr0 * xv.z; a0.w += pr0 * xv.w;
        a1.x += pr1 * xv.x; a1.y += pr1 * xv.y; a1.z += pr1 * xv.z; a1.w += pr1 * xv.w;
    }
    // butterfly across the 4 row-subsets (q groups)
#pragma unroll
    for (int o = 16; o <= 32; o <<= 1) {
        a0.x += __shfl_xor(a0.x, o, 64); a0.y += __shfl_xor(a0.y, o, 64);
        a0.z += __shfl_xor(a0.z, o, 64); a0.w += __shfl_xor(a0.w, o, 64);
        a1.x += __shfl_xor(a1.x, o, 64); a1.y += __shfl_xor(a1.y, o, 64);
        a1.z += __shfl_xor(a1.z, o, 64); a1.w += __shfl_xor(a1.w, o, 64);
    }

    float l0 = bf_sum(lsum0), l1 = bf_sum(lsum1);
    size_t obase = ((size_t)jc * BB * NN + b * NN + i0 + w2) * C1 + h * DH;
    if (lane < 16) {
        *(float4*)&pagg[obase + (c16 << 2)] = a0;           // row w2
    } else if (lane < 32) {
        *(float4*)&pagg[obase + C1 + (c16 << 2)] = a1;      // row w2+1
    }
    if (lane == 0) {
        plsum[((size_t)jc * HH * BB + h * BB + b) * NN + i0 + w2] = l0;
        plsum[((size_t)jc * HH * BB + h * BB + b) * NN + i0 + w2 + 1] = l1;
    }
}

// --- combine partials + final LayerNorm, wave-per-row ---
__global__ __launch_bounds__(256) void ln2_k(const float* __restrict__ pagg,
        const float* __restrict__ plsum, const float* __restrict__ abias,
        const float* __restrict__ g, const float* __restrict__ be,
        float* __restrict__ outp) {
    int t = threadIdx.x, lane = t & 63, w = t >> 6;
    int rgb = blockIdx.x * 4 + w;
    int bb = rgb >> 9, ii = rgb & 511;
    int c4 = lane << 2, hh = lane >> 4;
    float vx = 0.f, vy = 0.f, vz = 0.f, vw = 0.f, l = 0.f;
#pragma unroll
    for (int jc = 0; jc < NJC; jc++) {
        float4 a = *(const float4*)(pagg + ((size_t)jc * BB * NN + rgb) * C1 + c4);
        vx += a.x; vy += a.y; vz += a.z; vw += a.w;
        l += plsum[((size_t)jc * HH * BB + hh * BB + bb) * NN + ii];
    }
    float inv = 1.f / l;
    float4 bi = *(const float4*)(abias + c4);
    vx = vx * inv + bi.x; vy = vy * inv + bi.y;
    vz = vz * inv + bi.z; vw = vw * inv + bi.w;
    float mu = bf_sum(vx + vy + vz + vw) * (1.f / 256.f);
    float dx = vx - mu, dy = vy - mu, dz = vz - mu, dw = vw - mu;
    float var = bf_sum(dx * dx + dy * dy + dz * dz + dw * dw) * (1.f / 256.f);
    float rs = rsqrtf(var + LEPS);
    float4 gv = *(const float4*)(g + c4);
    float4 bv = *(const float4*)(be + c4);
    float4 y;
    y.x = dx * rs * gv.x + bv.x;
    y.y = dy * rs * gv.y + bv.y;
    y.z = dz * rs * gv.z + bv.z;
    y.w = dw * rs * gv.w + bv.w;
    *(float4*)(outp + (size_t)rgb * C1 + c4) = y;
}

extern "C" void kernel_launch(void* const* d_in, const int* in_sizes, int n_in,
                              void* d_out, int out_size, void* d_ws, size_t ws_size,
                              hipStream_t stream) {
    const float* x    = (const float*)d_in[0];
    const float* emb  = (const float*)d_in[1];
    const float* w1l  = (const float*)d_in[2];
    const float* b1l  = (const float*)d_in[3];
    const float* w1r  = (const float*)d_in[4];
    const float* b1r  = (const float*)d_in[5];
    const float* att1 = (const float*)d_in[6];
    const float* bia1 = (const float*)d_in[7];
    const float* g1   = (const float*)d_in[8];
    const float* be1  = (const float*)d_in[9];
    const float* w2l  = (const float*)d_in[10];
    const float* b2l  = (const float*)d_in[11];
    const float* w2r  = (const float*)d_in[12];
    const float* b2r  = (const float*)d_in[13];
    const float* att2 = (const float*)d_in[14];
    const float* bia2 = (const float*)d_in[15];
    const float* g2   = (const float*)d_in[16];
    const float* be2  = (const float*)d_in[17];

    char* w = (char*)d_ws;
    float* xl    = (float*)w; w += (size_t)BB * NN * C1 * 4;
    float* xr    = (float*)w; w += (size_t)BB * NN * C1 * 4;
    float* pagg  = (float*)w; w += (size_t)NJC * BB * NN * C1 * 4;
    u64* mask64  = (u64*)w;   w += (size_t)NN * 8 * 8;
    float* plsum = (float*)w; w += (size_t)NJC * HH * BB * NN * 4;
    float* sl    = (float*)w; w += (size_t)HH * BB * NN * 4;
    float* sr    = (float*)w; w += (size_t)HH * BB * NN * 4;

    mask_k<<<dim3(NN / 16, 8), 256, 0, stream>>>(emb, mask64);
    proj1_k<<<dim3(BB * NN / 4, 4), 256, 0, stream>>>(x, w1l, b1l, w1r, b1r, att1, xl, xr, sl, sr);
    attn_k<<<dim3((NN / TI) * NJC, HH, BB), 256, 0, stream>>>(xl, xr, att1, mask64, sl, sr, pagg, plsum);
    projln_k<<<dim3(BB * NN / 4, 4), 256, 0, stream>>>(pagg, plsum, bia1, g1, be1,
                                                       w2l, b2l, w2r, b2r, att2, xl, xr, sl, sr);
    attn_k<<<dim3((NN / TI) * NJC, HH, BB), 256, 0, stream>>>(xl, xr, att2, mask64, sl, sr, pagg, plsum);
    ln2_k<<<BB * NN / 4, 256, 0, stream>>>(pagg, plsum, bia2, g2, be2, (float*)d_out);
}